// Round 2
// baseline (1174.654 us; speedup 1.0000x reference)
//
#include <hip/hip_runtime.h>
#include <stdint.h>

#define BATCH 4
#define CH    256
#define NTOK  4096
#define KSEL  409          // int(0.1 * 4096)

typedef unsigned short u16;
typedef unsigned int   u32;
typedef unsigned long long u64;

typedef __attribute__((ext_vector_type(8))) _Float16 half8;
typedef __attribute__((ext_vector_type(4))) float f32x4;
typedef __attribute__((ext_vector_type(4))) u32 u32x4;
typedef __attribute__((ext_vector_type(2))) u32 u32x2;
typedef __attribute__((ext_vector_type(4))) float fl4;

// ---------------- helpers ----------------
__device__ inline u16 h2u(_Float16 h){ u16 u; __builtin_memcpy(&u,&h,2); return u; }
__device__ inline float h2f(u16 v){ _Float16 h; __builtin_memcpy(&h,&v,2); return (float)h; }
// monotone float<->uint key transform (ascending)
__device__ inline float keyinv(u32 k){ u32 v=(k&0x80000000u)?(k^0x80000000u):~k; return __uint_as_float(v); }
__device__ inline void gload16(const void* g, void* l){
  __builtin_amdgcn_global_load_lds((const __attribute__((address_space(1))) u32*)g,
                                   (__attribute__((address_space(3))) u32*)l, 16, 0, 0);
}

// ---------------- phase 0: QKV projections ----------------
// x:[B,CH,NTOK] f32; W:[CH(out),CH(in)] f32.
// Qh/Ql,Kh/Kl: fp16 hi/lo split [B,NTOK,CH]; Vt: fp16 [B,NTOK,CH]
__global__ __launch_bounds__(256) void proj_kernel(
    const float* __restrict__ x, const float* __restrict__ Wq,
    const float* __restrict__ Wk, const float* __restrict__ Wv,
    u16* __restrict__ Qh, u16* __restrict__ Ql,
    u16* __restrict__ Kh, u16* __restrict__ Kl,
    u16* __restrict__ Vt)
{
  const int tid  = threadIdx.x;
  const int b    = blockIdx.x >> 4;
  const int n    = ((blockIdx.x & 15) << 8) + tid;   // token
  const int p    = blockIdx.y;                       // 0=Q 1=K 2=V
  const int dblk = blockIdx.z << 6;                  // 64 out-channels per block

  const float* W  = (p==0)? Wq : (p==1)? Wk : Wv;
  const float* xb = x + (size_t)b*CH*NTOK + n;

  float acc[64];
  #pragma unroll
  for (int i=0;i<64;i++) acc[i]=0.f;

  for (int c=0;c<CH;c+=4) {
    float x0 = xb[(size_t)(c+0)*NTOK];
    float x1 = xb[(size_t)(c+1)*NTOK];
    float x2 = xb[(size_t)(c+2)*NTOK];
    float x3 = xb[(size_t)(c+3)*NTOK];
    #pragma unroll
    for (int dd=0;dd<64;dd++) {
      const float* wr = W + (size_t)(dblk+dd)*CH + c;   // uniform -> s_load
      float a = acc[dd];
      a = fmaf(x0, wr[0], a);
      a = fmaf(x1, wr[1], a);
      a = fmaf(x2, wr[2], a);
      a = fmaf(x3, wr[3], a);
      acc[dd]=a;
    }
  }

  const size_t base = ((size_t)b*NTOK + n)*CH + dblk;
  if (p < 2) {           // fp16 hi/lo split
    u16* oh = ((p==0)? Qh : Kh) + base;
    u16* ol = ((p==0)? Ql : Kl) + base;
    #pragma unroll
    for (int g=0; g<8; g++) {
      u32x4 vh, vl;
      #pragma unroll
      for (int q=0;q<4;q++) {
        float a0 = acc[g*8+q*2], a1 = acc[g*8+q*2+1];
        _Float16 h0 = (_Float16)a0, h1 = (_Float16)a1;
        _Float16 l0 = (_Float16)(a0 - (float)h0);
        _Float16 l1 = (_Float16)(a1 - (float)h1);
        vh[q] = (u32)h2u(h0) | ((u32)h2u(h1)<<16);
        vl[q] = (u32)h2u(l0) | ((u32)h2u(l1)<<16);
      }
      *(u32x4*)(oh + g*8) = vh;
      *(u32x4*)(ol + g*8) = vl;
    }
  } else {               // plain fp16
    u16* o = Vt + base;
    #pragma unroll
    for (int g=0; g<8; g++) {
      u32x4 v;
      #pragma unroll
      for (int q=0;q<4;q++) {
        _Float16 h0 = (_Float16)acc[g*8+q*2];
        _Float16 h1 = (_Float16)acc[g*8+q*2+1];
        v[q] = (u32)h2u(h0) | ((u32)h2u(h1)<<16);
      }
      *(u32x4*)(o + g*8) = v;
    }
  }
}

// ---------------- phase 1: S = Q*K^T / 16 (one batch), fp32-equivalent ----------------
// split-fp16: S = Ah*Bh + Ah*Bl + Al*Bh  (3 MFMAs, one fp32 accumulator).
// 128x128 tile, BK=64, 4 waves (2x2 of 64x64), mfma_f32_16x16x32_f16.
// global_load_lds staging with pre-swizzled source; ds_read uses matching swizzle.
__global__ __launch_bounds__(256) void score_kernel(
    const u16* __restrict__ Qh, const u16* __restrict__ Ql,
    const u16* __restrict__ Kh, const u16* __restrict__ Kl,
    float* __restrict__ S, int b)
{
  __shared__ __align__(16) short lds_ah[128*64];
  __shared__ __align__(16) short lds_al[128*64];
  __shared__ __align__(16) short lds_bh[128*64];
  __shared__ __align__(16) short lds_bl[128*64];
  const int tid  = threadIdx.x;
  const int lane = tid & 63;
  const int wave = tid >> 6;
  const int wm = wave >> 1, wn = wave & 1;
  const int brow = blockIdx.x << 7, bcol = blockIdx.y << 7;

  const size_t aoff = ((size_t)b*NTOK + brow)*CH;
  const size_t boff = ((size_t)b*NTOK + bcol)*CH;
  const u16* Agh = Qh + aoff;
  const u16* Agl = Ql + aoff;
  const u16* Bgh = Kh + boff;
  const u16* Bgl = Kl + boff;

  f32x4 acc[4][4];
  #pragma unroll
  for (int i=0;i<4;i++)
    #pragma unroll
    for (int j=0;j<4;j++) acc[i][j] = (f32x4)0.f;

  const int sr    = tid >> 3;   // row within 32-row staging call
  const int sslot = tid & 7;    // 16B slot within 128B row

  for (int kt=0; kt<4; kt++) {
    #pragma unroll
    for (int c=0;c<4;c++) {
      int r  = (c<<5) + sr;
      int ss = sslot ^ (r & 7);                 // inverse-swizzled global slot
      size_t goff = (size_t)r*CH + (kt<<6) + (ss<<3);
      int dst = (c<<12) + (wave<<10);
      gload16(Agh + goff, (char*)lds_ah + dst);
      gload16(Agl + goff, (char*)lds_al + dst);
      gload16(Bgh + goff, (char*)lds_bh + dst);
      gload16(Bgl + goff, (char*)lds_bl + dst);
    }
    __syncthreads();
    #pragma unroll
    for (int ks=0;ks<2;ks++) {
      half8 ah[4], al[4], bh[4], bl[4];
      const int kg = lane >> 4;
      const int rl = lane & 15;
      #pragma unroll
      for (int t=0;t<4;t++) {
        int ar = (wm<<6) + (t<<4) + rl;
        int slot = (ks<<2) + kg;
        int ao = ar*64 + ((slot ^ (ar&7))<<3);
        ah[t] = *(const half8*)&lds_ah[ao];
        al[t] = *(const half8*)&lds_al[ao];
        int br = (wn<<6) + (t<<4) + rl;
        int bo = br*64 + ((slot ^ (br&7))<<3);
        bh[t] = *(const half8*)&lds_bh[bo];
        bl[t] = *(const half8*)&lds_bl[bo];
      }
      #pragma unroll
      for (int mt=0;mt<4;mt++)
        #pragma unroll
        for (int nt=0;nt<4;nt++) {
          acc[mt][nt] = __builtin_amdgcn_mfma_f32_16x16x32_f16(ah[mt], bh[nt], acc[mt][nt], 0,0,0);
          acc[mt][nt] = __builtin_amdgcn_mfma_f32_16x16x32_f16(ah[mt], bl[nt], acc[mt][nt], 0,0,0);
          acc[mt][nt] = __builtin_amdgcn_mfma_f32_16x16x32_f16(al[mt], bh[nt], acc[mt][nt], 0,0,0);
        }
    }
    __syncthreads();
  }

  const int rl = lane & 15, rg = lane >> 4;
  #pragma unroll
  for (int mt=0;mt<4;mt++) {
    #pragma unroll
    for (int nt=0;nt<4;nt++) {
      int row = brow + (wm<<6) + (mt<<4) + (rg<<2);
      int col = bcol + (wn<<6) + (nt<<4) + rl;
      #pragma unroll
      for (int r=0;r<4;r++)
        S[(size_t)(row+r)*NTOK + col] = acc[mt][nt][r] * 0.0625f;
    }
  }
}

// ---------------- phase 2: exact per-row top-KSEL -> (idx, weight) list ----------------
// one wave per row; keys in 64 VGPRs; 4x 8-bit radix passes with per-wave LDS histogram;
// ballot-ordered compaction (index order == jax.lax.top_k tie order). No __syncthreads.
__global__ __launch_bounds__(256) void select_kernel(
    const float* __restrict__ S, u32x2* __restrict__ list, int b)
{
  __shared__ __align__(16) u32 hist[4][256];
  const int lane = threadIdx.x & 63;
  const int wave = threadIdx.x >> 6;
  const int row  = (blockIdx.x << 2) + wave;     // row within batch
  const float* Srow = S + (size_t)row * NTOK;

  u32 key[64];
  float m = -3.4e38f;
  #pragma unroll
  for (int ch=0; ch<64; ch++) {
    float s = Srow[(ch<<6) + lane];              // element index = ch*64 + lane
    m = fmaxf(m, s);
    u32 u = __float_as_uint(s);
    key[ch] = (u & 0x80000000u) ? ~u : (u | 0x80000000u);
  }
  #pragma unroll
  for (int off=32; off; off>>=1) m = fmaxf(m, __shfl_xor(m, off, 64));

  u32 prefix = 0;
  int krem = KSEL;
  for (int pass=0; pass<4; pass++) {
    const int shift = 24 - (pass<<3);
    const u32 pmask = (pass==0)? 0u : (0xFFFFFFFFu << (shift+8));
    #pragma unroll
    for (int i=0;i<4;i++) hist[wave][(i<<6)+lane] = 0u;
    __asm__ volatile("s_waitcnt lgkmcnt(0)" ::: "memory");
    #pragma unroll
    for (int ch=0; ch<64; ch++) {
      u32 u = key[ch];
      if ((u & pmask) == prefix) atomicAdd(&hist[wave][(u>>shift)&255u], 1u);
    }
    __asm__ volatile("s_waitcnt lgkmcnt(0)" ::: "memory");
    u32x4 h = *(const u32x4*)&hist[wave][lane<<2];
    u32 tot = h[0]+h[1]+h[2]+h[3];
    u32 sfx = tot;
    #pragma unroll
    for (int off=1; off<64; off<<=1) {
      u32 v = __shfl_down(sfx, off, 64);
      if (lane + off < 64) sfx += v;
    }
    // suffix counts: s_j = count in bin j and all higher bins
    u32 s3 = (sfx - tot) + h[3];
    u32 s2 = s3 + h[2];
    u32 s1 = s2 + h[1];
    u32 s0 = s1 + h[0];
    u32 s4 = s3 - h[3];
    u32 kr = (u32)krem;
    u32 enc = 0;
    if (s0 >= kr && s1 < kr) enc = (u32)(((lane<<2)+0)<<9) | (kr - s1);
    if (s1 >= kr && s2 < kr) enc = (u32)(((lane<<2)+1)<<9) | (kr - s2);
    if (s2 >= kr && s3 < kr) enc = (u32)(((lane<<2)+2)<<9) | (kr - s3);
    if (s3 >= kr && s4 < kr) enc = (u32)(((lane<<2)+3)<<9) | (kr - s4);
    #pragma unroll
    for (int off=32; off; off>>=1) { u32 o = __shfl_xor(enc, off, 64); enc = (o>enc)? o:enc; }
    u32 digit = enc >> 9;
    krem = (int)(enc & 0x1FFu);
    prefix |= digit << shift;
  }

  const u32 tkey = prefix;                 // exact 409th-largest key
  const float tf = keyinv(tkey);
  float z = 0.f;
  #pragma unroll
  for (int ch=0; ch<64; ch++)
    if (key[ch] > tkey) z += __expf(keyinv(key[ch]) - m);
  #pragma unroll
  for (int off=32; off; off>>=1) z += __shfl_xor(z, off, 64);
  float Z = z + (float)krem * __expf(tf - m);
  float invZ = 1.f / Z;

  u32x2* lrow = list + ((size_t)b*NTOK + row) * KSEL;
  const u64 ltmask = (1ull << lane) - 1ull;
  int sbase = 0, eqbase = 0;
  #pragma unroll
  for (int ch=0; ch<64; ch++) {
    u32 u = key[ch];
    bool eq = (u == tkey);
    u64 eqm = __ballot(eq);
    bool sel = (u > tkey) || (eq && (eqbase + __popcll(eqm & ltmask)) < krem);
    u64 sm = __ballot(sel);
    if (sel) {
      int pos = sbase + __popcll(sm & ltmask);
      float w = __expf(keyinv(u) - m) * invZ;
      u32x2 pr; pr[0] = (u32)((ch<<6) + lane); pr[1] = __float_as_uint(w);
      lrow[pos] = pr;
    }
    sbase  += __popcll(sm);
    eqbase += __popcll(eqm);
  }
}

// ---------------- phase 3: sparse PV + transposed (channel-major) output ----------------
// wave per 4 rows sequentially; lane owns 4 channels; list entries via uniform loads.
__global__ __launch_bounds__(256) void pv_kernel(
    const u32x2* __restrict__ list, const u16* __restrict__ Vt,
    float* __restrict__ out)
{
  const int lane = threadIdx.x & 63;
  const int wave = __builtin_amdgcn_readfirstlane(threadIdx.x >> 6);
  const int row0 = (blockIdx.x << 4) + (wave << 2);   // global row (b*NTOK + n)
  const int b    = row0 >> 12;
  const u16* Vb  = Vt + (size_t)b * NTOK * CH;

  float acc[4][4];   // [row][channel-sub]
  #pragma unroll
  for (int i=0;i<4;i++)
    #pragma unroll
    for (int j=0;j<4;j++) acc[i][j]=0.f;

  #pragma unroll
  for (int r=0;r<4;r++) {
    const u32x2* lr = list + (size_t)(row0 + r) * KSEL;
    #pragma unroll 2
    for (int j=0;j<KSEL;j++) {
      u32x2 p = lr[j];
      int idx = (int)p[0];
      float w = __uint_as_float(p[1]);
      u32x2 q = *(const u32x2*)(Vb + (size_t)idx*CH + (lane<<2));  // 4 fp16
      acc[r][0] = fmaf(w, h2f((u16)(q[0] & 0xffffu)), acc[r][0]);
      acc[r][1] = fmaf(w, h2f((u16)(q[0] >> 16)),     acc[r][1]);
      acc[r][2] = fmaf(w, h2f((u16)(q[1] & 0xffffu)), acc[r][2]);
      acc[r][3] = fmaf(w, h2f((u16)(q[1] >> 16)),     acc[r][3]);
    }
  }
  const int n0 = row0 & (NTOK-1);
  #pragma unroll
  for (int cc=0; cc<4; cc++) {
    fl4 v; v[0]=acc[0][cc]; v[1]=acc[1][cc]; v[2]=acc[2][cc]; v[3]=acc[3][cc];
    int chn = (lane<<2) + cc;
    *(fl4*)&out[((size_t)b*CH + chn)*NTOK + n0] = v;   // 16B store, full lines per block
  }
}

// ---------------- launcher ----------------
extern "C" void kernel_launch(void* const* d_in, const int* in_sizes, int n_in,
                              void* d_out, int out_size, void* d_ws, size_t ws_size,
                              hipStream_t stream)
{
  (void)in_sizes; (void)n_in; (void)out_size; (void)ws_size;
  const float* x  = (const float*)d_in[0];
  const float* Wq = (const float*)d_in[1];
  const float* Wk = (const float*)d_in[2];
  const float* Wv = (const float*)d_in[3];
  float* out = (float*)d_out;

  char* ws = (char*)d_ws;
  size_t off = 0;
  const size_t plane = (size_t)BATCH*NTOK*CH*2;       // 8.4 MB fp16 plane
  u16* Qh = (u16*)(ws + off); off += plane;
  u16* Ql = (u16*)(ws + off); off += plane;
  u16* Kh = (u16*)(ws + off); off += plane;
  u16* Kl = (u16*)(ws + off); off += plane;
  u16* Vt = (u16*)(ws + off); off += plane;
  u32x2* list = (u32x2*)(ws + off); off += (size_t)BATCH*NTOK*KSEL*8; // 53.6 MB
  float* S = (float*)(ws + off);    off += (size_t)NTOK*NTOK*4;       // 67.1 MB (reused per batch)
  // total ws use ~163 MB

  proj_kernel<<<dim3(64,3,4), 256, 0, stream>>>(x, Wq, Wk, Wv, Qh, Ql, Kh, Kl, Vt);
  for (int b=0; b<BATCH; b++) {
    score_kernel<<<dim3(32,32), 256, 0, stream>>>(Qh, Ql, Kh, Kl, S, b);
    select_kernel<<<1024, 256, 0, stream>>>(S, list, b);
  }
  pv_kernel<<<1024, 256, 0, stream>>>(list, Vt, out);
}

// Round 3
// 698.947 us; speedup vs baseline: 1.6806x; 1.6806x over previous
//
#include <hip/hip_runtime.h>
#include <stdint.h>

#define BATCH 4
#define CH    256
#define NTOK  4096
#define KSEL  409          // int(0.1 * 4096)

typedef unsigned short u16;
typedef unsigned int   u32;
typedef unsigned long long u64;

typedef __attribute__((ext_vector_type(8))) _Float16 half8;
typedef __attribute__((ext_vector_type(4))) float f32x4;
typedef __attribute__((ext_vector_type(4))) u32 u32x4;

// ---------------- helpers ----------------
__device__ inline u16 h2u(_Float16 h){ u16 u; __builtin_memcpy(&u,&h,2); return u; }
// monotone float<->uint key transform (ascending)
__device__ inline float keyinv(u32 k){ u32 v=(k&0x80000000u)?(k^0x80000000u):~k; return __uint_as_float(v); }
__device__ inline void gload16(const void* g, void* l){
  __builtin_amdgcn_global_load_lds((const __attribute__((address_space(1))) u32*)g,
                                   (__attribute__((address_space(3))) u32*)l, 16, 0, 0);
}

// ---------------- phase 0: QKV projections ----------------
// x:[B,CH,NTOK] f32; W:[CH(out),CH(in)] f32.
// Qh/Ql,Kh/Kl: fp16 hi/lo split [B,NTOK,CH]; Vc: fp16 CHANNEL-major [B,CH,NTOK]
__global__ __launch_bounds__(256) void proj_kernel(
    const float* __restrict__ x, const float* __restrict__ Wq,
    const float* __restrict__ Wk, const float* __restrict__ Wv,
    u16* __restrict__ Qh, u16* __restrict__ Ql,
    u16* __restrict__ Kh, u16* __restrict__ Kl,
    u16* __restrict__ Vc)
{
  const int tid  = threadIdx.x;
  const int b    = blockIdx.x >> 4;
  const int n    = ((blockIdx.x & 15) << 8) + tid;   // token
  const int p    = blockIdx.y;                       // 0=Q 1=K 2=V
  const int dblk = blockIdx.z << 6;                  // 64 out-channels per block

  const float* W  = (p==0)? Wq : (p==1)? Wk : Wv;
  const float* xb = x + (size_t)b*CH*NTOK + n;

  float acc[64];
  #pragma unroll
  for (int i=0;i<64;i++) acc[i]=0.f;

  for (int c=0;c<CH;c+=4) {
    float x0 = xb[(size_t)(c+0)*NTOK];
    float x1 = xb[(size_t)(c+1)*NTOK];
    float x2 = xb[(size_t)(c+2)*NTOK];
    float x3 = xb[(size_t)(c+3)*NTOK];
    #pragma unroll
    for (int dd=0;dd<64;dd++) {
      const float* wr = W + (size_t)(dblk+dd)*CH + c;   // uniform -> s_load
      float a = acc[dd];
      a = fmaf(x0, wr[0], a);
      a = fmaf(x1, wr[1], a);
      a = fmaf(x2, wr[2], a);
      a = fmaf(x3, wr[3], a);
      acc[dd]=a;
    }
  }

  if (p < 2) {           // fp16 hi/lo split, token-major
    const size_t base = ((size_t)b*NTOK + n)*CH + dblk;
    u16* oh = ((p==0)? Qh : Kh) + base;
    u16* ol = ((p==0)? Ql : Kl) + base;
    #pragma unroll
    for (int g=0; g<8; g++) {
      u32x4 vh, vl;
      #pragma unroll
      for (int q=0;q<4;q++) {
        float a0 = acc[g*8+q*2], a1 = acc[g*8+q*2+1];
        _Float16 h0 = (_Float16)a0, h1 = (_Float16)a1;
        _Float16 l0 = (_Float16)(a0 - (float)h0);
        _Float16 l1 = (_Float16)(a1 - (float)h1);
        vh[q] = (u32)h2u(h0) | ((u32)h2u(h1)<<16);
        vl[q] = (u32)h2u(l0) | ((u32)h2u(l1)<<16);
      }
      *(u32x4*)(oh + g*8) = vh;
      *(u32x4*)(ol + g*8) = vl;
    }
  } else {               // plain fp16, channel-major: Vc[b][c][n]
    u16* o = Vc + (size_t)b*CH*NTOK + (size_t)dblk*NTOK + n;
    #pragma unroll
    for (int dd=0; dd<64; dd++)
      o[(size_t)dd*NTOK] = h2u((_Float16)acc[dd]);
  }
}

// ---------------- phase 1: S = Q*K^T / 16 (one batch), fp32-equivalent ----------------
// split-fp16: S = Ah*Bh + Ah*Bl + Al*Bh  (3 MFMAs, one fp32 accumulator).
// 128x128 tile, BK=64, 4 waves (2x2 of 64x64), mfma_f32_16x16x32_f16.
__global__ __launch_bounds__(256) void score_kernel(
    const u16* __restrict__ Qh, const u16* __restrict__ Ql,
    const u16* __restrict__ Kh, const u16* __restrict__ Kl,
    float* __restrict__ S, int b)
{
  __shared__ __align__(16) short lds_ah[128*64];
  __shared__ __align__(16) short lds_al[128*64];
  __shared__ __align__(16) short lds_bh[128*64];
  __shared__ __align__(16) short lds_bl[128*64];
  const int tid  = threadIdx.x;
  const int lane = tid & 63;
  const int wave = tid >> 6;
  const int wm = wave >> 1, wn = wave & 1;
  const int brow = blockIdx.x << 7, bcol = blockIdx.y << 7;

  const size_t aoff = ((size_t)b*NTOK + brow)*CH;
  const size_t boff = ((size_t)b*NTOK + bcol)*CH;
  const u16* Agh = Qh + aoff;
  const u16* Agl = Ql + aoff;
  const u16* Bgh = Kh + boff;
  const u16* Bgl = Kl + boff;

  f32x4 acc[4][4];
  #pragma unroll
  for (int i=0;i<4;i++)
    #pragma unroll
    for (int j=0;j<4;j++) acc[i][j] = (f32x4)0.f;

  const int sr    = tid >> 3;   // row within 32-row staging call
  const int sslot = tid & 7;    // 16B slot within 128B row

  for (int kt=0; kt<4; kt++) {
    #pragma unroll
    for (int c=0;c<4;c++) {
      int r  = (c<<5) + sr;
      int ss = sslot ^ (r & 7);                 // inverse-swizzled global slot
      size_t goff = (size_t)r*CH + (kt<<6) + (ss<<3);
      int dst = (c<<12) + (wave<<10);
      gload16(Agh + goff, (char*)lds_ah + dst);
      gload16(Agl + goff, (char*)lds_al + dst);
      gload16(Bgh + goff, (char*)lds_bh + dst);
      gload16(Bgl + goff, (char*)lds_bl + dst);
    }
    __syncthreads();
    #pragma unroll
    for (int ks=0;ks<2;ks++) {
      half8 ah[4], al[4], bh[4], bl[4];
      const int kg = lane >> 4;
      const int rl = lane & 15;
      #pragma unroll
      for (int t=0;t<4;t++) {
        int ar = (wm<<6) + (t<<4) + rl;
        int slot = (ks<<2) + kg;
        int ao = ar*64 + ((slot ^ (ar&7))<<3);
        ah[t] = *(const half8*)&lds_ah[ao];
        al[t] = *(const half8*)&lds_al[ao];
        int br = (wn<<6) + (t<<4) + rl;
        int bo = br*64 + ((slot ^ (br&7))<<3);
        bh[t] = *(const half8*)&lds_bh[bo];
        bl[t] = *(const half8*)&lds_bl[bo];
      }
      #pragma unroll
      for (int mt=0;mt<4;mt++)
        #pragma unroll
        for (int nt=0;nt<4;nt++) {
          acc[mt][nt] = __builtin_amdgcn_mfma_f32_16x16x32_f16(ah[mt], bh[nt], acc[mt][nt], 0,0,0);
          acc[mt][nt] = __builtin_amdgcn_mfma_f32_16x16x32_f16(ah[mt], bl[nt], acc[mt][nt], 0,0,0);
          acc[mt][nt] = __builtin_amdgcn_mfma_f32_16x16x32_f16(al[mt], bh[nt], acc[mt][nt], 0,0,0);
        }
    }
    __syncthreads();
  }

  const int rl = lane & 15, rg = lane >> 4;
  #pragma unroll
  for (int mt=0;mt<4;mt++) {
    #pragma unroll
    for (int nt=0;nt<4;nt++) {
      int row = brow + (wm<<6) + (mt<<4) + (rg<<2);
      int col = bcol + (wn<<6) + (nt<<4) + rl;
      #pragma unroll
      for (int r=0;r<4;r++)
        S[(size_t)(row+r)*NTOK + col] = acc[mt][nt][r] * 0.0625f;
    }
  }
}

// ---------------- phase 2: exact per-row top-KSEL -> dense fp16 weight row ----------------
// one wave per row; keys in 64 VGPRs; 4x 8-bit radix passes with per-wave LDS histogram;
// tie inclusion in index order == jax.lax.top_k. Writes softmax weight (or 0) densely.
__global__ __launch_bounds__(256) void select_kernel(
    const float* __restrict__ S, u16* __restrict__ Wd)
{
  __shared__ __align__(16) u32 hist[4][256];
  const int lane = threadIdx.x & 63;
  const int wave = threadIdx.x >> 6;
  const int row  = (blockIdx.x << 2) + wave;     // row within batch
  const float* Srow = S + (size_t)row * NTOK;

  u32 key[64];
  float m = -3.4e38f;
  #pragma unroll
  for (int ch=0; ch<64; ch++) {
    float s = Srow[(ch<<6) + lane];              // element index = ch*64 + lane
    m = fmaxf(m, s);
    u32 u = __float_as_uint(s);
    key[ch] = (u & 0x80000000u) ? ~u : (u | 0x80000000u);
  }
  #pragma unroll
  for (int off=32; off; off>>=1) m = fmaxf(m, __shfl_xor(m, off, 64));

  u32 prefix = 0;
  int krem = KSEL;
  for (int pass=0; pass<4; pass++) {
    const int shift = 24 - (pass<<3);
    const u32 pmask = (pass==0)? 0u : (0xFFFFFFFFu << (shift+8));
    #pragma unroll
    for (int i=0;i<4;i++) hist[wave][(i<<6)+lane] = 0u;
    __asm__ volatile("s_waitcnt lgkmcnt(0)" ::: "memory");
    #pragma unroll
    for (int ch=0; ch<64; ch++) {
      u32 u = key[ch];
      if ((u & pmask) == prefix) atomicAdd(&hist[wave][(u>>shift)&255u], 1u);
    }
    __asm__ volatile("s_waitcnt lgkmcnt(0)" ::: "memory");
    u32x4 h = *(const u32x4*)&hist[wave][lane<<2];
    u32 tot = h[0]+h[1]+h[2]+h[3];
    u32 sfx = tot;
    #pragma unroll
    for (int off=1; off<64; off<<=1) {
      u32 v = __shfl_down(sfx, off, 64);
      if (lane + off < 64) sfx += v;
    }
    // suffix counts: s_j = count in bin j and all higher bins
    u32 s3 = (sfx - tot) + h[3];
    u32 s2 = s3 + h[2];
    u32 s1 = s2 + h[1];
    u32 s0 = s1 + h[0];
    u32 s4 = s3 - h[3];
    u32 kr = (u32)krem;
    u32 enc = 0;
    if (s0 >= kr && s1 < kr) enc = (u32)(((lane<<2)+0)<<9) | (kr - s1);
    if (s1 >= kr && s2 < kr) enc = (u32)(((lane<<2)+1)<<9) | (kr - s2);
    if (s2 >= kr && s3 < kr) enc = (u32)(((lane<<2)+2)<<9) | (kr - s3);
    if (s3 >= kr && s4 < kr) enc = (u32)(((lane<<2)+3)<<9) | (kr - s4);
    #pragma unroll
    for (int off=32; off; off>>=1) { u32 o = __shfl_xor(enc, off, 64); enc = (o>enc)? o:enc; }
    u32 digit = enc >> 9;
    krem = (int)(enc & 0x1FFu);
    prefix |= digit << shift;
  }

  const u32 tkey = prefix;                 // exact KSEL-th-largest key
  const float tf = keyinv(tkey);
  float z = 0.f;
  #pragma unroll
  for (int ch=0; ch<64; ch++)
    if (key[ch] > tkey) z += __expf(keyinv(key[ch]) - m);
  #pragma unroll
  for (int off=32; off; off>>=1) z += __shfl_xor(z, off, 64);
  float Z = z + (float)krem * __expf(tf - m);
  float invZ = 1.f / Z;

  u16* wrow = Wd + (size_t)row * NTOK;
  const u64 ltmask = (1ull << lane) - 1ull;
  int eqbase = 0;
  #pragma unroll
  for (int ch=0; ch<64; ch++) {
    u32 u = key[ch];
    bool eq = (u == tkey);
    u64 eqm = __ballot(eq);
    bool sel = (u > tkey) || (eq && (eqbase + __popcll(eqm & ltmask)) < krem);
    float w = sel ? (__expf(keyinv(u) - m) * invZ) : 0.f;
    wrow[(ch<<6) + lane] = h2u((_Float16)w);
    eqbase += __popcll(eqm);
  }
}

// ---------------- phase 3: dense PV GEMM ----------------
// out^T[c,n] = sum_k Vc[c,k] * Wd[n,k]  -> writes final [B,CH,NTOK] directly.
// 128x128 tile over (c, n), K=NTOK, BK=64, same structure as score_kernel, fp16 MFMA.
__global__ __launch_bounds__(256) void pv_gemm(
    const u16* __restrict__ Vc, const u16* __restrict__ Wd,
    float* __restrict__ out, int b_base, size_t wstride)
{
  __shared__ __align__(16) short lds_a[128*64];
  __shared__ __align__(16) short lds_b[128*64];
  const int tid  = threadIdx.x;
  const int lane = tid & 63;
  const int wave = tid >> 6;
  const int wm = wave >> 1, wn = wave & 1;
  const int b    = b_base + blockIdx.z;
  const int brow = blockIdx.x << 7;      // channel tile (0 / 128)
  const int bcol = blockIdx.y << 7;      // token (query) tile

  const u16* Ag = Vc + (size_t)b*CH*NTOK + (size_t)brow*NTOK;
  const u16* Bg = Wd + (size_t)blockIdx.z*wstride + (size_t)bcol*NTOK;

  f32x4 acc[4][4];
  #pragma unroll
  for (int i=0;i<4;i++)
    #pragma unroll
    for (int j=0;j<4;j++) acc[i][j] = (f32x4)0.f;

  const int sr    = tid >> 3;
  const int sslot = tid & 7;

  for (int kt=0; kt<64; kt++) {
    #pragma unroll
    for (int c=0;c<4;c++) {
      int r  = (c<<5) + sr;
      int ss = sslot ^ (r & 7);
      size_t goff = (size_t)r*NTOK + (kt<<6) + (ss<<3);
      int dst = (c<<12) + (wave<<10);
      gload16(Ag + goff, (char*)lds_a + dst);
      gload16(Bg + goff, (char*)lds_b + dst);
    }
    __syncthreads();
    #pragma unroll
    for (int ks=0;ks<2;ks++) {
      half8 af[4], bf[4];
      const int kg = lane >> 4;
      const int rl = lane & 15;
      #pragma unroll
      for (int t=0;t<4;t++) {
        int ar = (wm<<6) + (t<<4) + rl;
        int slot = (ks<<2) + kg;
        af[t] = *(const half8*)&lds_a[ar*64 + ((slot ^ (ar&7))<<3)];
        int br = (wn<<6) + (t<<4) + rl;
        bf[t] = *(const half8*)&lds_b[br*64 + ((slot ^ (br&7))<<3)];
      }
      #pragma unroll
      for (int mt=0;mt<4;mt++)
        #pragma unroll
        for (int nt=0;nt<4;nt++)
          acc[mt][nt] = __builtin_amdgcn_mfma_f32_16x16x32_f16(af[mt], bf[nt], acc[mt][nt], 0,0,0);
    }
    __syncthreads();
  }

  float* ob = out + (size_t)b*CH*NTOK;
  const int rl = lane & 15, rg = lane >> 4;
  #pragma unroll
  for (int mt=0;mt<4;mt++) {
    #pragma unroll
    for (int nt=0;nt<4;nt++) {
      int row = brow + (wm<<6) + (mt<<4) + (rg<<2);   // channel
      int col = bcol + (wn<<6) + (nt<<4) + rl;        // token
      #pragma unroll
      for (int r=0;r<4;r++)
        ob[(size_t)(row+r)*NTOK + col] = acc[mt][nt][r];
    }
  }
}

// ---------------- launcher ----------------
extern "C" void kernel_launch(void* const* d_in, const int* in_sizes, int n_in,
                              void* d_out, int out_size, void* d_ws, size_t ws_size,
                              hipStream_t stream)
{
  (void)in_sizes; (void)n_in; (void)out_size;
  const float* x  = (const float*)d_in[0];
  const float* Wq = (const float*)d_in[1];
  const float* Wk = (const float*)d_in[2];
  const float* Wv = (const float*)d_in[3];
  float* out = (float*)d_out;

  char* ws = (char*)d_ws;
  size_t off = 0;
  const size_t plane = (size_t)BATCH*NTOK*CH*2;       // 8.4 MB fp16 plane
  const size_t NN    = (size_t)NTOK*NTOK;             // 16.8M elements
  u16* Qh = (u16*)(ws + off); off += plane;
  u16* Ql = (u16*)(ws + off); off += plane;
  u16* Kh = (u16*)(ws + off); off += plane;
  u16* Kl = (u16*)(ws + off); off += plane;
  u16* Vc = (u16*)(ws + off); off += plane;
  // need: W (fp16) + S (fp32, single-batch, reused)
  const size_t fullW_need = off + (size_t)BATCH*NN*2 + NN*4;   // ~232 MiB
  const bool fullW = ws_size >= fullW_need;
  u16* Wd = (u16*)(ws + off); off += (fullW ? (size_t)BATCH*NN*2 : NN*2);
  float* S = (float*)(ws + off);

  proj_kernel<<<dim3(64,3,4), 256, 0, stream>>>(x, Wq, Wk, Wv, Qh, Ql, Kh, Kl, Vc);

  if (fullW) {
    for (int b=0; b<BATCH; b++) {
      score_kernel<<<dim3(32,32), 256, 0, stream>>>(Qh, Ql, Kh, Kl, S, b);
      select_kernel<<<1024, 256, 0, stream>>>(S, Wd + (size_t)b*NN);
    }
    pv_gemm<<<dim3(2,32,4), 256, 0, stream>>>(Vc, Wd, out, 0, NN);
  } else {
    for (int b=0; b<BATCH; b++) {
      score_kernel<<<dim3(32,32), 256, 0, stream>>>(Qh, Ql, Kh, Kl, S, b);
      select_kernel<<<1024, 256, 0, stream>>>(S, Wd);
      pv_gemm<<<dim3(2,32,1), 256, 0, stream>>>(Vc, Wd, out, b, 0);
    }
  }
}

// Round 4
// 484.227 us; speedup vs baseline: 2.4258x; 1.4434x over previous
//
#include <hip/hip_runtime.h>
#include <stdint.h>

#define BATCH 4
#define CH    256
#define NTOK  4096
#define KSEL  409          // int(0.1 * 4096)

typedef unsigned short u16;
typedef unsigned int   u32;
typedef unsigned long long u64;

typedef __attribute__((ext_vector_type(8))) _Float16 half8;
typedef __attribute__((ext_vector_type(4))) _Float16 half4;
typedef __attribute__((ext_vector_type(4))) float f32x4;
typedef __attribute__((ext_vector_type(4))) u32 u32x4;
typedef __attribute__((ext_vector_type(2))) u32 u32x2;
typedef __attribute__((ext_vector_type(4))) float fl4;

// ---------------- helpers ----------------
__device__ inline u16 h2u(_Float16 h){ u16 u; __builtin_memcpy(&u,&h,2); return u; }
// monotone float<->uint key transform (ascending)
__device__ inline float keyinv(u32 k){ u32 v=(k&0x80000000u)?(k^0x80000000u):~k; return __uint_as_float(v); }
__device__ inline void gload16(const void* g, void* l){
  __builtin_amdgcn_global_load_lds((const __attribute__((address_space(1))) u32*)g,
                                   (__attribute__((address_space(3))) u32*)l, 16, 0, 0);
}

// ---------------- phase -1: W split ----------------
// Wq/Wk/Wv [CH][CH] f32 -> W3h/W3l [3][CH][CH] fp16 hi/lo
__global__ __launch_bounds__(256) void wsplit_kernel(
    const float* __restrict__ Wq, const float* __restrict__ Wk,
    const float* __restrict__ Wv, u16* __restrict__ W3h, u16* __restrict__ W3l)
{
  const int p = blockIdx.y;
  const float* W = (p==0)? Wq : (p==1)? Wk : Wv;
  const int idx = (blockIdx.x*256 + threadIdx.x) * 4;   // 64 blocks * 256 * 4 = 65536
  fl4 v = *(const fl4*)(W + idx);
  u32x2 vh, vl;
  #pragma unroll
  for (int q=0;q<2;q++) {
    _Float16 h0=(_Float16)v[q*2], h1=(_Float16)v[q*2+1];
    _Float16 l0=(_Float16)(v[q*2]-(float)h0), l1=(_Float16)(v[q*2+1]-(float)h1);
    vh[q] = (u32)h2u(h0) | ((u32)h2u(h1)<<16);
    vl[q] = (u32)h2u(l0) | ((u32)h2u(l1)<<16);
  }
  *(u32x2*)(W3h + p*CH*CH + idx) = vh;
  *(u32x2*)(W3l + p*CH*CH + idx) = vl;
}

// ---------------- phase 0a: x transpose + split ----------------
// x [B][CH][NTOK] f32 -> xTh/xTl [B][NTOK][CH] fp16 hi/lo (64x64 LDS tiles)
__global__ __launch_bounds__(256) void xsplit_kernel(
    const float* __restrict__ x, u16* __restrict__ xTh, u16* __restrict__ xTl)
{
  __shared__ float lds[64][65];
  const int tid = threadIdx.x;
  const int n0 = blockIdx.x << 6;
  const int c0 = blockIdx.y << 6;
  const int b  = blockIdx.z;
  const float* xb = x + (size_t)b*CH*NTOK;

  #pragma unroll
  for (int i=0;i<16;i++) {
    int c_l = (tid>>6) + (i<<2);
    int n_l = tid & 63;
    lds[c_l][n_l] = xb[(size_t)(c0+c_l)*NTOK + n0 + n_l];
  }
  __syncthreads();
  u16* oh = xTh + (size_t)b*NTOK*CH;
  u16* ol = xTl + (size_t)b*NTOK*CH;
  #pragma unroll
  for (int i=0;i<16;i++) {
    int n_l = (tid>>6) + (i<<2);
    int c_l = tid & 63;
    float v = lds[c_l][n_l];
    _Float16 h = (_Float16)v;
    _Float16 l = (_Float16)(v - (float)h);
    size_t o = (size_t)(n0+n_l)*CH + c0 + c_l;
    oh[o] = h2u(h);
    ol[o] = h2u(l);
  }
}

// ---------------- phase 0b: QKV projection GEMM ----------------
// out[n][d] = sum_c xT[n][c] * W[d][c], fp32-equivalent via 3-term split-fp16 MFMA.
// 128x128 tile, K=256 (4 kt), 4 waves. p<2: store hi/lo token-major; p==2: V channel-major.
__global__ __launch_bounds__(256) void proj_gemm(
    const u16* __restrict__ xTh, const u16* __restrict__ xTl,
    const u16* __restrict__ W3h, const u16* __restrict__ W3l,
    u16* __restrict__ Qh, u16* __restrict__ Ql,
    u16* __restrict__ Kh, u16* __restrict__ Kl,
    u16* __restrict__ Vc)
{
  __shared__ __align__(16) short lds[4*128*64];   // ah, al, bh, bl (16KB each)
  short* lds_ah = lds;
  short* lds_al = lds + 128*64;
  short* lds_bh = lds + 2*128*64;
  short* lds_bl = lds + 3*128*64;

  const int tid  = threadIdx.x;
  const int lane = tid & 63;
  const int wave = tid >> 6;
  const int wm = wave >> 1, wn = wave & 1;
  const int brow = blockIdx.x << 7;     // token tile
  const int bcol = blockIdx.y << 7;     // out-channel tile
  const int z = blockIdx.z;             // b*3 + p
  const int b = z / 3, p = z - 3*b;

  const u16* Agh = xTh + ((size_t)b*NTOK + brow)*CH;
  const u16* Agl = xTl + ((size_t)b*NTOK + brow)*CH;
  const u16* Bgh = W3h + (size_t)p*CH*CH + (size_t)bcol*CH;
  const u16* Bgl = W3l + (size_t)p*CH*CH + (size_t)bcol*CH;

  f32x4 acc[4][4];
  #pragma unroll
  for (int i=0;i<4;i++)
    #pragma unroll
    for (int j=0;j<4;j++) acc[i][j] = (f32x4)0.f;

  const int sr    = tid >> 3;
  const int sslot = tid & 7;

  for (int kt=0; kt<4; kt++) {
    #pragma unroll
    for (int c=0;c<4;c++) {
      int r  = (c<<5) + sr;
      int ss = sslot ^ (r & 7);
      size_t goff = (size_t)r*CH + (kt<<6) + (ss<<3);
      int dst = (c<<12) + (wave<<10);
      gload16(Agh + goff, (char*)lds_ah + dst);
      gload16(Agl + goff, (char*)lds_al + dst);
      gload16(Bgh + goff, (char*)lds_bh + dst);
      gload16(Bgl + goff, (char*)lds_bl + dst);
    }
    __syncthreads();
    #pragma unroll
    for (int ks=0;ks<2;ks++) {
      half8 ah[4], al[4], bh[4], bl[4];
      const int kg = lane >> 4;
      const int rl = lane & 15;
      #pragma unroll
      for (int t=0;t<4;t++) {
        int ar = (wm<<6) + (t<<4) + rl;
        int slot = (ks<<2) + kg;
        int ao = ar*64 + ((slot ^ (ar&7))<<3);
        ah[t] = *(const half8*)&lds_ah[ao];
        al[t] = *(const half8*)&lds_al[ao];
        int br = (wn<<6) + (t<<4) + rl;
        int bo = br*64 + ((slot ^ (br&7))<<3);
        bh[t] = *(const half8*)&lds_bh[bo];
        bl[t] = *(const half8*)&lds_bl[bo];
      }
      #pragma unroll
      for (int mt=0;mt<4;mt++)
        #pragma unroll
        for (int nt=0;nt<4;nt++) {
          acc[mt][nt] = __builtin_amdgcn_mfma_f32_16x16x32_f16(ah[mt], bh[nt], acc[mt][nt], 0,0,0);
          acc[mt][nt] = __builtin_amdgcn_mfma_f32_16x16x32_f16(ah[mt], bl[nt], acc[mt][nt], 0,0,0);
          acc[mt][nt] = __builtin_amdgcn_mfma_f32_16x16x32_f16(al[mt], bh[nt], acc[mt][nt], 0,0,0);
        }
    }
    __syncthreads();
  }

  const int rl = lane & 15, rg = lane >> 4;
  if (p < 2) {
    // hi/lo re-split, token-major [b][n][c]
    u16* oh = ((p==0)? Qh : Kh) + (size_t)b*NTOK*CH;
    u16* ol = ((p==0)? Ql : Kl) + (size_t)b*NTOK*CH;
    #pragma unroll
    for (int mt=0;mt<4;mt++) {
      #pragma unroll
      for (int nt=0;nt<4;nt++) {
        int n = brow + (wm<<6) + (mt<<4) + (rg<<2);
        int c = bcol + (wn<<6) + (nt<<4) + rl;
        #pragma unroll
        for (int r=0;r<4;r++) {
          float v = acc[mt][nt][r];
          _Float16 h = (_Float16)v;
          _Float16 l = (_Float16)(v - (float)h);
          size_t o = (size_t)(n+r)*CH + c;
          oh[o] = h2u(h);
          ol[o] = h2u(l);
        }
      }
    }
  } else {
    // V: transpose in LDS -> store channel-major Vc[b][d][n] coalesced
    u16* ldsT = (u16*)lds;                 // [128][136] u16 = 34816 B
    #pragma unroll
    for (int mt=0;mt<4;mt++) {
      #pragma unroll
      for (int nt=0;nt<4;nt++) {
        int n_l = (wm<<6) + (mt<<4) + (rg<<2);
        int c_l = (wn<<6) + (nt<<4) + rl;
        half4 hv;
        #pragma unroll
        for (int r=0;r<4;r++) hv[r] = (_Float16)acc[mt][nt][r];
        *(half4*)&ldsT[c_l*136 + n_l] = hv;
      }
    }
    __syncthreads();
    u16* ov = Vc + (size_t)b*CH*NTOK + (size_t)bcol*NTOK + brow;
    #pragma unroll
    for (int i=0;i<32;i++) {
      int d_l = (tid>>6) + (i<<2);
      u32 v = *(const u32*)&ldsT[d_l*136 + (lane<<1)];
      *(u32*)(ov + (size_t)d_l*NTOK + (lane<<1)) = v;
    }
  }
}

// ---------------- phase 1: S = Q*K^T / 16 (one batch), fp32-equivalent ----------------
__global__ __launch_bounds__(256) void score_kernel(
    const u16* __restrict__ Qh, const u16* __restrict__ Ql,
    const u16* __restrict__ Kh, const u16* __restrict__ Kl,
    float* __restrict__ S, int b)
{
  __shared__ __align__(16) short lds_ah[128*64];
  __shared__ __align__(16) short lds_al[128*64];
  __shared__ __align__(16) short lds_bh[128*64];
  __shared__ __align__(16) short lds_bl[128*64];
  const int tid  = threadIdx.x;
  const int lane = tid & 63;
  const int wave = tid >> 6;
  const int wm = wave >> 1, wn = wave & 1;
  const int brow = blockIdx.x << 7, bcol = blockIdx.y << 7;

  const size_t aoff = ((size_t)b*NTOK + brow)*CH;
  const size_t boff = ((size_t)b*NTOK + bcol)*CH;
  const u16* Agh = Qh + aoff;
  const u16* Agl = Ql + aoff;
  const u16* Bgh = Kh + boff;
  const u16* Bgl = Kl + boff;

  f32x4 acc[4][4];
  #pragma unroll
  for (int i=0;i<4;i++)
    #pragma unroll
    for (int j=0;j<4;j++) acc[i][j] = (f32x4)0.f;

  const int sr    = tid >> 3;
  const int sslot = tid & 7;

  for (int kt=0; kt<4; kt++) {
    #pragma unroll
    for (int c=0;c<4;c++) {
      int r  = (c<<5) + sr;
      int ss = sslot ^ (r & 7);
      size_t goff = (size_t)r*CH + (kt<<6) + (ss<<3);
      int dst = (c<<12) + (wave<<10);
      gload16(Agh + goff, (char*)lds_ah + dst);
      gload16(Agl + goff, (char*)lds_al + dst);
      gload16(Bgh + goff, (char*)lds_bh + dst);
      gload16(Bgl + goff, (char*)lds_bl + dst);
    }
    __syncthreads();
    #pragma unroll
    for (int ks=0;ks<2;ks++) {
      half8 ah[4], al[4], bh[4], bl[4];
      const int kg = lane >> 4;
      const int rl = lane & 15;
      #pragma unroll
      for (int t=0;t<4;t++) {
        int ar = (wm<<6) + (t<<4) + rl;
        int slot = (ks<<2) + kg;
        int ao = ar*64 + ((slot ^ (ar&7))<<3);
        ah[t] = *(const half8*)&lds_ah[ao];
        al[t] = *(const half8*)&lds_al[ao];
        int br = (wn<<6) + (t<<4) + rl;
        int bo = br*64 + ((slot ^ (br&7))<<3);
        bh[t] = *(const half8*)&lds_bh[bo];
        bl[t] = *(const half8*)&lds_bl[bo];
      }
      #pragma unroll
      for (int mt=0;mt<4;mt++)
        #pragma unroll
        for (int nt=0;nt<4;nt++) {
          acc[mt][nt] = __builtin_amdgcn_mfma_f32_16x16x32_f16(ah[mt], bh[nt], acc[mt][nt], 0,0,0);
          acc[mt][nt] = __builtin_amdgcn_mfma_f32_16x16x32_f16(ah[mt], bl[nt], acc[mt][nt], 0,0,0);
          acc[mt][nt] = __builtin_amdgcn_mfma_f32_16x16x32_f16(al[mt], bh[nt], acc[mt][nt], 0,0,0);
        }
    }
    __syncthreads();
  }

  const int rl = lane & 15, rg = lane >> 4;
  #pragma unroll
  for (int mt=0;mt<4;mt++) {
    #pragma unroll
    for (int nt=0;nt<4;nt++) {
      int row = brow + (wm<<6) + (mt<<4) + (rg<<2);
      int col = bcol + (wn<<6) + (nt<<4) + rl;
      #pragma unroll
      for (int r=0;r<4;r++)
        S[(size_t)(row+r)*NTOK + col] = acc[mt][nt][r] * 0.0625f;
    }
  }
}

// ---------------- phase 2: exact per-row top-KSEL -> dense fp16 weight row ----------------
__global__ __launch_bounds__(256) void select_kernel(
    const float* __restrict__ S, u16* __restrict__ Wd)
{
  __shared__ __align__(16) u32 hist[4][256];
  const int lane = threadIdx.x & 63;
  const int wave = threadIdx.x >> 6;
  const int row  = (blockIdx.x << 2) + wave;
  const float* Srow = S + (size_t)row * NTOK;

  u32 key[64];
  float m = -3.4e38f;
  #pragma unroll
  for (int ch=0; ch<64; ch++) {
    float s = Srow[(ch<<6) + lane];
    m = fmaxf(m, s);
    u32 u = __float_as_uint(s);
    key[ch] = (u & 0x80000000u) ? ~u : (u | 0x80000000u);
  }
  #pragma unroll
  for (int off=32; off; off>>=1) m = fmaxf(m, __shfl_xor(m, off, 64));

  u32 prefix = 0;
  int krem = KSEL;
  for (int pass=0; pass<4; pass++) {
    const int shift = 24 - (pass<<3);
    const u32 pmask = (pass==0)? 0u : (0xFFFFFFFFu << (shift+8));
    #pragma unroll
    for (int i=0;i<4;i++) hist[wave][(i<<6)+lane] = 0u;
    __asm__ volatile("s_waitcnt lgkmcnt(0)" ::: "memory");
    #pragma unroll
    for (int ch=0; ch<64; ch++) {
      u32 u = key[ch];
      if ((u & pmask) == prefix) atomicAdd(&hist[wave][(u>>shift)&255u], 1u);
    }
    __asm__ volatile("s_waitcnt lgkmcnt(0)" ::: "memory");
    u32x4 h = *(const u32x4*)&hist[wave][lane<<2];
    u32 tot = h[0]+h[1]+h[2]+h[3];
    u32 sfx = tot;
    #pragma unroll
    for (int off=1; off<64; off<<=1) {
      u32 v = __shfl_down(sfx, off, 64);
      if (lane + off < 64) sfx += v;
    }
    u32 s3 = (sfx - tot) + h[3];
    u32 s2 = s3 + h[2];
    u32 s1 = s2 + h[1];
    u32 s0 = s1 + h[0];
    u32 s4 = s3 - h[3];
    u32 kr = (u32)krem;
    u32 enc = 0;
    if (s0 >= kr && s1 < kr) enc = (u32)(((lane<<2)+0)<<9) | (kr - s1);
    if (s1 >= kr && s2 < kr) enc = (u32)(((lane<<2)+1)<<9) | (kr - s2);
    if (s2 >= kr && s3 < kr) enc = (u32)(((lane<<2)+2)<<9) | (kr - s3);
    if (s3 >= kr && s4 < kr) enc = (u32)(((lane<<2)+3)<<9) | (kr - s4);
    #pragma unroll
    for (int off=32; off; off>>=1) { u32 o = __shfl_xor(enc, off, 64); enc = (o>enc)? o:enc; }
    u32 digit = enc >> 9;
    krem = (int)(enc & 0x1FFu);
    prefix |= digit << shift;
  }

  const u32 tkey = prefix;
  const float tf = keyinv(tkey);
  float z = 0.f;
  #pragma unroll
  for (int ch=0; ch<64; ch++)
    if (key[ch] > tkey) z += __expf(keyinv(key[ch]) - m);
  #pragma unroll
  for (int off=32; off; off>>=1) z += __shfl_xor(z, off, 64);
  float Z = z + (float)krem * __expf(tf - m);
  float invZ = 1.f / Z;

  u16* wrow = Wd + (size_t)row * NTOK;
  const u64 ltmask = (1ull << lane) - 1ull;
  int eqbase = 0;
  #pragma unroll
  for (int ch=0; ch<64; ch++) {
    u32 u = key[ch];
    bool eq = (u == tkey);
    u64 eqm = __ballot(eq);
    bool sel = (u > tkey) || (eq && (eqbase + __popcll(eqm & ltmask)) < krem);
    float w = sel ? (__expf(keyinv(u) - m) * invZ) : 0.f;
    wrow[(ch<<6) + lane] = h2u((_Float16)w);
    eqbase += __popcll(eqm);
  }
}

// ---------------- phase 3: dense PV GEMM ----------------
__global__ __launch_bounds__(256) void pv_gemm(
    const u16* __restrict__ Vc, const u16* __restrict__ Wd,
    float* __restrict__ out, int b_base, size_t wstride)
{
  __shared__ __align__(16) short lds_a[128*64];
  __shared__ __align__(16) short lds_b[128*64];
  const int tid  = threadIdx.x;
  const int lane = tid & 63;
  const int wave = tid >> 6;
  const int wm = wave >> 1, wn = wave & 1;
  const int b    = b_base + blockIdx.z;
  const int brow = blockIdx.x << 7;      // channel tile
  const int bcol = blockIdx.y << 7;      // token tile

  const u16* Ag = Vc + (size_t)b*CH*NTOK + (size_t)brow*NTOK;
  const u16* Bg = Wd + (size_t)blockIdx.z*wstride + (size_t)bcol*NTOK;

  f32x4 acc[4][4];
  #pragma unroll
  for (int i=0;i<4;i++)
    #pragma unroll
    for (int j=0;j<4;j++) acc[i][j] = (f32x4)0.f;

  const int sr    = tid >> 3;
  const int sslot = tid & 7;

  for (int kt=0; kt<64; kt++) {
    #pragma unroll
    for (int c=0;c<4;c++) {
      int r  = (c<<5) + sr;
      int ss = sslot ^ (r & 7);
      size_t goff = (size_t)r*NTOK + (kt<<6) + (ss<<3);
      int dst = (c<<12) + (wave<<10);
      gload16(Ag + goff, (char*)lds_a + dst);
      gload16(Bg + goff, (char*)lds_b + dst);
    }
    __syncthreads();
    #pragma unroll
    for (int ks=0;ks<2;ks++) {
      half8 af[4], bf[4];
      const int kg = lane >> 4;
      const int rl = lane & 15;
      #pragma unroll
      for (int t=0;t<4;t++) {
        int ar = (wm<<6) + (t<<4) + rl;
        int slot = (ks<<2) + kg;
        af[t] = *(const half8*)&lds_a[ar*64 + ((slot ^ (ar&7))<<3)];
        int br = (wn<<6) + (t<<4) + rl;
        bf[t] = *(const half8*)&lds_b[br*64 + ((slot ^ (br&7))<<3)];
      }
      #pragma unroll
      for (int mt=0;mt<4;mt++)
        #pragma unroll
        for (int nt=0;nt<4;nt++)
          acc[mt][nt] = __builtin_amdgcn_mfma_f32_16x16x32_f16(af[mt], bf[nt], acc[mt][nt], 0,0,0);
    }
    __syncthreads();
  }

  float* ob = out + (size_t)b*CH*NTOK;
  const int rl = lane & 15, rg = lane >> 4;
  #pragma unroll
  for (int mt=0;mt<4;mt++) {
    #pragma unroll
    for (int nt=0;nt<4;nt++) {
      int row = brow + (wm<<6) + (mt<<4) + (rg<<2);
      int col = bcol + (wn<<6) + (nt<<4) + rl;
      #pragma unroll
      for (int r=0;r<4;r++)
        ob[(size_t)(row+r)*NTOK + col] = acc[mt][nt][r];
    }
  }
}

// ---------------- launcher ----------------
extern "C" void kernel_launch(void* const* d_in, const int* in_sizes, int n_in,
                              void* d_out, int out_size, void* d_ws, size_t ws_size,
                              hipStream_t stream)
{
  (void)in_sizes; (void)n_in; (void)out_size;
  const float* x  = (const float*)d_in[0];
  const float* Wq = (const float*)d_in[1];
  const float* Wk = (const float*)d_in[2];
  const float* Wv = (const float*)d_in[3];
  float* out = (float*)d_out;

  char* ws = (char*)d_ws;
  size_t off = 0;
  const size_t plane = (size_t)BATCH*NTOK*CH*2;       // 8.4 MB fp16 plane
  const size_t NN    = (size_t)NTOK*NTOK;             // 16.8M elements
  u16* Qh = (u16*)(ws + off); off += plane;
  u16* Ql = (u16*)(ws + off); off += plane;
  u16* Kh = (u16*)(ws + off); off += plane;
  u16* Kl = (u16*)(ws + off); off += plane;
  u16* Vc = (u16*)(ws + off); off += plane;
  u16* W3h = (u16*)(ws + off); off += (size_t)3*CH*CH*2;
  u16* W3l = (u16*)(ws + off); off += (size_t)3*CH*CH*2;
  // xT planes live only until proj_gemm completes; Wd overlaps them afterwards.
  const size_t xt_base = off;
  u16* xTh = (u16*)(ws + xt_base);
  u16* xTl = (u16*)(ws + xt_base + plane);
  const size_t fullW_need = xt_base + (size_t)BATCH*NN*2 + NN*4;   // ~244 MiB
  const bool fullW = ws_size >= fullW_need;
  u16* Wd = (u16*)(ws + xt_base);
  float* S = (float*)(ws + xt_base + (fullW ? (size_t)BATCH*NN*2 : NN*2));

  wsplit_kernel<<<dim3(64,3), 256, 0, stream>>>(Wq, Wk, Wv, W3h, W3l);
  xsplit_kernel<<<dim3(64,4,4), 256, 0, stream>>>(x, xTh, xTl);
  proj_gemm<<<dim3(32,2,12), 256, 0, stream>>>(xTh, xTl, W3h, W3l, Qh, Ql, Kh, Kl, Vc);

  if (fullW) {
    for (int b=0; b<BATCH; b++) {
      score_kernel<<<dim3(32,32), 256, 0, stream>>>(Qh, Ql, Kh, Kl, S, b);
      select_kernel<<<1024, 256, 0, stream>>>(S, Wd + (size_t)b*NN);
    }
    pv_gemm<<<dim3(2,32,4), 256, 0, stream>>>(Vc, Wd, out, 0, NN);
  } else {
    for (int b=0; b<BATCH; b++) {
      score_kernel<<<dim3(32,32), 256, 0, stream>>>(Qh, Ql, Kh, Kl, S, b);
      select_kernel<<<1024, 256, 0, stream>>>(S, Wd);
      pv_gemm<<<dim3(2,32,1), 256, 0, stream>>>(Vc, Wd, out, b, 0);
    }
  }
}

// Round 5
// 428.859 us; speedup vs baseline: 2.7390x; 1.1291x over previous
//
#include <hip/hip_runtime.h>
#include <stdint.h>

#define BATCH 4
#define CH    256
#define NTOK  4096
#define KSEL  409          // int(0.1 * 4096)

typedef unsigned short u16;
typedef unsigned int   u32;
typedef unsigned long long u64;

typedef __attribute__((ext_vector_type(8))) _Float16 half8;
typedef __attribute__((ext_vector_type(4))) _Float16 half4;
typedef __attribute__((ext_vector_type(4))) float f32x4;
typedef __attribute__((ext_vector_type(4))) u32 u32x4;
typedef __attribute__((ext_vector_type(2))) u32 u32x2;
typedef __attribute__((ext_vector_type(4))) float fl4;

// ---------------- helpers ----------------
__device__ inline u16 h2u(_Float16 h){ u16 u; __builtin_memcpy(&u,&h,2); return u; }
// monotone float<->uint key transform (ascending)
__device__ inline float keyinv(u32 k){ u32 v=(k&0x80000000u)?(k^0x80000000u):~k; return __uint_as_float(v); }
__device__ inline void gload16(const void* g, void* l){
  __builtin_amdgcn_global_load_lds((const __attribute__((address_space(1))) u32*)g,
                                   (__attribute__((address_space(3))) u32*)l, 16, 0, 0);
}

// ---------------- phase -1: W split ----------------
// Wq/Wk/Wv [CH][CH] f32 -> W3h/W3l [3][CH][CH] fp16 hi/lo
__global__ __launch_bounds__(256) void wsplit_kernel(
    const float* __restrict__ Wq, const float* __restrict__ Wk,
    const float* __restrict__ Wv, u16* __restrict__ W3h, u16* __restrict__ W3l)
{
  const int p = blockIdx.y;
  const float* W = (p==0)? Wq : (p==1)? Wk : Wv;
  const int idx = (blockIdx.x*256 + threadIdx.x) * 4;
  fl4 v = *(const fl4*)(W + idx);
  u32x2 vh, vl;
  #pragma unroll
  for (int q=0;q<2;q++) {
    _Float16 h0=(_Float16)v[q*2], h1=(_Float16)v[q*2+1];
    _Float16 l0=(_Float16)(v[q*2]-(float)h0), l1=(_Float16)(v[q*2+1]-(float)h1);
    vh[q] = (u32)h2u(h0) | ((u32)h2u(h1)<<16);
    vl[q] = (u32)h2u(l0) | ((u32)h2u(l1)<<16);
  }
  *(u32x2*)(W3h + p*CH*CH + idx) = vh;
  *(u32x2*)(W3l + p*CH*CH + idx) = vl;
}

// ---------------- phase 0a: x transpose + split ----------------
// x [B][CH][NTOK] f32 -> xTh/xTl [B][NTOK][CH] fp16 hi/lo (64x64 LDS tiles)
__global__ __launch_bounds__(256) void xsplit_kernel(
    const float* __restrict__ x, u16* __restrict__ xTh, u16* __restrict__ xTl)
{
  __shared__ float lds[64][65];
  const int tid = threadIdx.x;
  const int n0 = blockIdx.x << 6;
  const int c0 = blockIdx.y << 6;
  const int b  = blockIdx.z;
  const float* xb = x + (size_t)b*CH*NTOK;

  #pragma unroll
  for (int i=0;i<16;i++) {
    int c_l = (tid>>6) + (i<<2);
    int n_l = tid & 63;
    lds[c_l][n_l] = xb[(size_t)(c0+c_l)*NTOK + n0 + n_l];
  }
  __syncthreads();
  u16* oh = xTh + (size_t)b*NTOK*CH;
  u16* ol = xTl + (size_t)b*NTOK*CH;
  #pragma unroll
  for (int i=0;i<16;i++) {
    int n_l = (tid>>6) + (i<<2);
    int c_l = tid & 63;
    float v = lds[c_l][n_l];
    _Float16 h = (_Float16)v;
    _Float16 l = (_Float16)(v - (float)h);
    size_t o = (size_t)(n0+n_l)*CH + c0 + c_l;
    oh[o] = h2u(h);
    ol[o] = h2u(l);
  }
}

// ---------------- phase 0b: QKV projection GEMM ----------------
// out[n][d] = sum_c xT[n][c] * W[d][c], fp32-equivalent via 3-term split-fp16 MFMA.
// Q/K stored fp16 (hi rounding only); V channel-major fp16.
__global__ __launch_bounds__(256) void proj_gemm(
    const u16* __restrict__ xTh, const u16* __restrict__ xTl,
    const u16* __restrict__ W3h, const u16* __restrict__ W3l,
    u16* __restrict__ Qh, u16* __restrict__ Kh, u16* __restrict__ Vc)
{
  __shared__ __align__(16) short lds[4*128*64];   // ah, al, bh, bl (16KB each)
  short* lds_ah = lds;
  short* lds_al = lds + 128*64;
  short* lds_bh = lds + 2*128*64;
  short* lds_bl = lds + 3*128*64;

  const int tid  = threadIdx.x;
  const int lane = tid & 63;
  const int wave = tid >> 6;
  const int wm = wave >> 1, wn = wave & 1;
  const int brow = blockIdx.x << 7;     // token tile
  const int bcol = blockIdx.y << 7;     // out-channel tile
  const int z = blockIdx.z;             // b*3 + p
  const int b = z / 3, p = z - 3*b;

  const u16* Agh = xTh + ((size_t)b*NTOK + brow)*CH;
  const u16* Agl = xTl + ((size_t)b*NTOK + brow)*CH;
  const u16* Bgh = W3h + (size_t)p*CH*CH + (size_t)bcol*CH;
  const u16* Bgl = W3l + (size_t)p*CH*CH + (size_t)bcol*CH;

  f32x4 acc[4][4];
  #pragma unroll
  for (int i=0;i<4;i++)
    #pragma unroll
    for (int j=0;j<4;j++) acc[i][j] = (f32x4)0.f;

  const int sr    = tid >> 3;
  const int sslot = tid & 7;

  for (int kt=0; kt<4; kt++) {
    #pragma unroll
    for (int c=0;c<4;c++) {
      int r  = (c<<5) + sr;
      int ss = sslot ^ (r & 7);
      size_t goff = (size_t)r*CH + (kt<<6) + (ss<<3);
      int dst = (c<<12) + (wave<<10);
      gload16(Agh + goff, (char*)lds_ah + dst);
      gload16(Agl + goff, (char*)lds_al + dst);
      gload16(Bgh + goff, (char*)lds_bh + dst);
      gload16(Bgl + goff, (char*)lds_bl + dst);
    }
    __syncthreads();
    #pragma unroll
    for (int ks=0;ks<2;ks++) {
      half8 ah[4], al[4], bh[4], bl[4];
      const int kg = lane >> 4;
      const int rl = lane & 15;
      #pragma unroll
      for (int t=0;t<4;t++) {
        int ar = (wm<<6) + (t<<4) + rl;
        int slot = (ks<<2) + kg;
        int ao = ar*64 + ((slot ^ (ar&7))<<3);
        ah[t] = *(const half8*)&lds_ah[ao];
        al[t] = *(const half8*)&lds_al[ao];
        int br = (wn<<6) + (t<<4) + rl;
        int bo = br*64 + ((slot ^ (br&7))<<3);
        bh[t] = *(const half8*)&lds_bh[bo];
        bl[t] = *(const half8*)&lds_bl[bo];
      }
      #pragma unroll
      for (int mt=0;mt<4;mt++)
        #pragma unroll
        for (int nt=0;nt<4;nt++) {
          acc[mt][nt] = __builtin_amdgcn_mfma_f32_16x16x32_f16(ah[mt], bh[nt], acc[mt][nt], 0,0,0);
          acc[mt][nt] = __builtin_amdgcn_mfma_f32_16x16x32_f16(ah[mt], bl[nt], acc[mt][nt], 0,0,0);
          acc[mt][nt] = __builtin_amdgcn_mfma_f32_16x16x32_f16(al[mt], bh[nt], acc[mt][nt], 0,0,0);
        }
    }
    __syncthreads();
  }

  const int rl = lane & 15, rg = lane >> 4;
  if (p < 2) {
    // fp16 (hi only), token-major [b][n][c]
    u16* oh = ((p==0)? Qh : Kh) + (size_t)b*NTOK*CH;
    #pragma unroll
    for (int mt=0;mt<4;mt++) {
      #pragma unroll
      for (int nt=0;nt<4;nt++) {
        int n = brow + (wm<<6) + (mt<<4) + (rg<<2);
        int c = bcol + (wn<<6) + (nt<<4) + rl;
        #pragma unroll
        for (int r=0;r<4;r++)
          oh[(size_t)(n+r)*CH + c] = h2u((_Float16)acc[mt][nt][r]);
      }
    }
  } else {
    // V: transpose in LDS -> store channel-major Vc[b][d][n] coalesced
    u16* ldsT = (u16*)lds;                 // [128][136] u16 = 34816 B
    #pragma unroll
    for (int mt=0;mt<4;mt++) {
      #pragma unroll
      for (int nt=0;nt<4;nt++) {
        int n_l = (wm<<6) + (mt<<4) + (rg<<2);
        int c_l = (wn<<6) + (nt<<4) + rl;
        half4 hv;
        #pragma unroll
        for (int r=0;r<4;r++) hv[r] = (_Float16)acc[mt][nt][r];
        *(half4*)&ldsT[c_l*136 + n_l] = hv;
      }
    }
    __syncthreads();
    u16* ov = Vc + (size_t)b*CH*NTOK + (size_t)bcol*NTOK + brow;
    #pragma unroll
    for (int i=0;i<32;i++) {
      int d_l = (tid>>6) + (i<<2);
      u32 v = *(const u32*)&ldsT[d_l*136 + (lane<<1)];
      *(u32*)(ov + (size_t)d_l*NTOK + (lane<<1)) = v;
    }
  }
}

// ---------------- phase 1: S = Q*K^T / 16 (one batch), hi-only fp16 ----------------
// plain fp16 GEMM: 128x128 tile, K=256, 4 waves. Score noise sigma ~4e-4.
__global__ __launch_bounds__(256) void score_kernel(
    const u16* __restrict__ Qh, const u16* __restrict__ Kh,
    float* __restrict__ S, int b)
{
  __shared__ __align__(16) short lds_a[128*64];
  __shared__ __align__(16) short lds_b[128*64];
  const int tid  = threadIdx.x;
  const int lane = tid & 63;
  const int wave = tid >> 6;
  const int wm = wave >> 1, wn = wave & 1;
  const int brow = blockIdx.x << 7, bcol = blockIdx.y << 7;

  const u16* Ag = Qh + ((size_t)b*NTOK + brow)*CH;
  const u16* Bg = Kh + ((size_t)b*NTOK + bcol)*CH;

  f32x4 acc[4][4];
  #pragma unroll
  for (int i=0;i<4;i++)
    #pragma unroll
    for (int j=0;j<4;j++) acc[i][j] = (f32x4)0.f;

  const int sr    = tid >> 3;
  const int sslot = tid & 7;

  for (int kt=0; kt<4; kt++) {
    #pragma unroll
    for (int c=0;c<4;c++) {
      int r  = (c<<5) + sr;
      int ss = sslot ^ (r & 7);
      size_t goff = (size_t)r*CH + (kt<<6) + (ss<<3);
      int dst = (c<<12) + (wave<<10);
      gload16(Ag + goff, (char*)lds_a + dst);
      gload16(Bg + goff, (char*)lds_b + dst);
    }
    __syncthreads();
    #pragma unroll
    for (int ks=0;ks<2;ks++) {
      half8 af[4], bf[4];
      const int kg = lane >> 4;
      const int rl = lane & 15;
      #pragma unroll
      for (int t=0;t<4;t++) {
        int ar = (wm<<6) + (t<<4) + rl;
        int slot = (ks<<2) + kg;
        af[t] = *(const half8*)&lds_a[ar*64 + ((slot ^ (ar&7))<<3)];
        int br = (wn<<6) + (t<<4) + rl;
        bf[t] = *(const half8*)&lds_b[br*64 + ((slot ^ (br&7))<<3)];
      }
      #pragma unroll
      for (int mt=0;mt<4;mt++)
        #pragma unroll
        for (int nt=0;nt<4;nt++)
          acc[mt][nt] = __builtin_amdgcn_mfma_f32_16x16x32_f16(af[mt], bf[nt], acc[mt][nt], 0,0,0);
    }
    __syncthreads();
  }

  const int rl = lane & 15, rg = lane >> 4;
  #pragma unroll
  for (int mt=0;mt<4;mt++) {
    #pragma unroll
    for (int nt=0;nt<4;nt++) {
      int row = brow + (wm<<6) + (mt<<4) + (rg<<2);
      int col = bcol + (wn<<6) + (nt<<4) + rl;
      #pragma unroll
      for (int r=0;r<4;r++)
        S[(size_t)(row+r)*NTOK + col] = acc[mt][nt][r] * 0.0625f;
    }
  }
}

// ---------------- phase 2: exact per-row top-KSEL -> dense fp16 weight row ----------------
__global__ __launch_bounds__(256) void select_kernel(
    const float* __restrict__ S, u16* __restrict__ Wd)
{
  __shared__ __align__(16) u32 hist[4][256];
  const int lane = threadIdx.x & 63;
  const int wave = threadIdx.x >> 6;
  const int row  = (blockIdx.x << 2) + wave;
  const float* Srow = S + (size_t)row * NTOK;

  u32 key[64];
  float m = -3.4e38f;
  #pragma unroll
  for (int ch=0; ch<64; ch++) {
    float s = Srow[(ch<<6) + lane];
    m = fmaxf(m, s);
    u32 u = __float_as_uint(s);
    key[ch] = (u & 0x80000000u) ? ~u : (u | 0x80000000u);
  }
  #pragma unroll
  for (int off=32; off; off>>=1) m = fmaxf(m, __shfl_xor(m, off, 64));

  u32 prefix = 0;
  int krem = KSEL;
  for (int pass=0; pass<4; pass++) {
    const int shift = 24 - (pass<<3);
    const u32 pmask = (pass==0)? 0u : (0xFFFFFFFFu << (shift+8));
    #pragma unroll
    for (int i=0;i<4;i++) hist[wave][(i<<6)+lane] = 0u;
    __asm__ volatile("s_waitcnt lgkmcnt(0)" ::: "memory");
    #pragma unroll
    for (int ch=0; ch<64; ch++) {
      u32 u = key[ch];
      if ((u & pmask) == prefix) atomicAdd(&hist[wave][(u>>shift)&255u], 1u);
    }
    __asm__ volatile("s_waitcnt lgkmcnt(0)" ::: "memory");
    u32x4 h = *(const u32x4*)&hist[wave][lane<<2];
    u32 tot = h[0]+h[1]+h[2]+h[3];
    u32 sfx = tot;
    #pragma unroll
    for (int off=1; off<64; off<<=1) {
      u32 v = __shfl_down(sfx, off, 64);
      if (lane + off < 64) sfx += v;
    }
    u32 s3 = (sfx - tot) + h[3];
    u32 s2 = s3 + h[2];
    u32 s1 = s2 + h[1];
    u32 s0 = s1 + h[0];
    u32 s4 = s3 - h[3];
    u32 kr = (u32)krem;
    u32 enc = 0;
    if (s0 >= kr && s1 < kr) enc = (u32)(((lane<<2)+0)<<9) | (kr - s1);
    if (s1 >= kr && s2 < kr) enc = (u32)(((lane<<2)+1)<<9) | (kr - s2);
    if (s2 >= kr && s3 < kr) enc = (u32)(((lane<<2)+2)<<9) | (kr - s3);
    if (s3 >= kr && s4 < kr) enc = (u32)(((lane<<2)+3)<<9) | (kr - s4);
    #pragma unroll
    for (int off=32; off; off>>=1) { u32 o = __shfl_xor(enc, off, 64); enc = (o>enc)? o:enc; }
    u32 digit = enc >> 9;
    krem = (int)(enc & 0x1FFu);
    prefix |= digit << shift;
  }

  const u32 tkey = prefix;
  const float tf = keyinv(tkey);
  float z = 0.f;
  #pragma unroll
  for (int ch=0; ch<64; ch++)
    if (key[ch] > tkey) z += __expf(keyinv(key[ch]) - m);
  #pragma unroll
  for (int off=32; off; off>>=1) z += __shfl_xor(z, off, 64);
  float Z = z + (float)krem * __expf(tf - m);
  float invZ = 1.f / Z;

  u16* wrow = Wd + (size_t)row * NTOK;
  const u64 ltmask = (1ull << lane) - 1ull;
  int eqbase = 0;
  #pragma unroll
  for (int ch=0; ch<64; ch++) {
    u32 u = key[ch];
    bool eq = (u == tkey);
    u64 eqm = __ballot(eq);
    bool sel = (u > tkey) || (eq && (eqbase + __popcll(eqm & ltmask)) < krem);
    float w = sel ? (__expf(keyinv(u) - m) * invZ) : 0.f;
    wrow[(ch<<6) + lane] = h2u((_Float16)w);
    eqbase += __popcll(eqm);
  }
}

// ---------------- phase 3: dense PV GEMM ----------------
// out^T[c,n] = sum_k Vc[c,k] * Wd[n,k].  128(M=ch) x 64(N=tok) tiles, K=NTOK.
// grid (2, 64, BATCH) = 512 blocks -> 2 blocks/CU for wave overlap.
__global__ __launch_bounds__(256) void pv_gemm(
    const u16* __restrict__ Vc, const u16* __restrict__ Wd,
    float* __restrict__ out, int b_base, size_t wstride)
{
  __shared__ __align__(16) short lds_a[128*64];   // 16 KB
  __shared__ __align__(16) short lds_b[64*64];    //  8 KB
  const int tid  = threadIdx.x;
  const int lane = tid & 63;
  const int wave = tid >> 6;
  const int wm = wave >> 1, wn = wave & 1;
  const int b    = b_base + blockIdx.z;
  const int brow = blockIdx.x << 7;      // channel tile (0/128)
  const int bcol = blockIdx.y << 6;      // token tile (64-wide)

  const u16* Ag = Vc + (size_t)b*CH*NTOK + (size_t)brow*NTOK;
  const u16* Bg = Wd + (size_t)blockIdx.z*wstride + (size_t)bcol*NTOK;

  f32x4 acc[4][2];
  #pragma unroll
  for (int i=0;i<4;i++)
    #pragma unroll
    for (int j=0;j<2;j++) acc[i][j] = (f32x4)0.f;

  const int sr    = tid >> 3;
  const int sslot = tid & 7;

  for (int kt=0; kt<64; kt++) {
    #pragma unroll
    for (int c=0;c<4;c++) {
      int r  = (c<<5) + sr;
      int ss = sslot ^ (r & 7);
      size_t goff = (size_t)r*NTOK + (kt<<6) + (ss<<3);
      gload16(Ag + goff, (char*)lds_a + (c<<12) + (wave<<10));
    }
    #pragma unroll
    for (int c=0;c<2;c++) {
      int r  = (c<<5) + sr;
      int ss = sslot ^ (r & 7);
      size_t goff = (size_t)r*NTOK + (kt<<6) + (ss<<3);
      gload16(Bg + goff, (char*)lds_b + (c<<12) + (wave<<10));
    }
    __syncthreads();
    #pragma unroll
    for (int ks=0;ks<2;ks++) {
      half8 af[4], bf[2];
      const int kg = lane >> 4;
      const int rl = lane & 15;
      const int slot = (ks<<2) + kg;
      #pragma unroll
      for (int t=0;t<4;t++) {
        int ar = (wm<<6) + (t<<4) + rl;
        af[t] = *(const half8*)&lds_a[ar*64 + ((slot ^ (ar&7))<<3)];
      }
      #pragma unroll
      for (int t=0;t<2;t++) {
        int br = (wn<<5) + (t<<4) + rl;
        bf[t] = *(const half8*)&lds_b[br*64 + ((slot ^ (br&7))<<3)];
      }
      #pragma unroll
      for (int mt=0;mt<4;mt++)
        #pragma unroll
        for (int nt=0;nt<2;nt++)
          acc[mt][nt] = __builtin_amdgcn_mfma_f32_16x16x32_f16(af[mt], bf[nt], acc[mt][nt], 0,0,0);
    }
    __syncthreads();
  }

  float* ob = out + (size_t)b*CH*NTOK;
  const int rl = lane & 15, rg = lane >> 4;
  #pragma unroll
  for (int mt=0;mt<4;mt++) {
    #pragma unroll
    for (int nt=0;nt<2;nt++) {
      int row = brow + (wm<<6) + (mt<<4) + (rg<<2);   // channel
      int col = bcol + (wn<<5) + (nt<<4) + rl;        // token
      #pragma unroll
      for (int r=0;r<4;r++)
        ob[(size_t)(row+r)*NTOK + col] = acc[mt][nt][r];
    }
  }
}

// ---------------- launcher ----------------
extern "C" void kernel_launch(void* const* d_in, const int* in_sizes, int n_in,
                              void* d_out, int out_size, void* d_ws, size_t ws_size,
                              hipStream_t stream)
{
  (void)in_sizes; (void)n_in; (void)out_size;
  const float* x  = (const float*)d_in[0];
  const float* Wq = (const float*)d_in[1];
  const float* Wk = (const float*)d_in[2];
  const float* Wv = (const float*)d_in[3];
  float* out = (float*)d_out;

  char* ws = (char*)d_ws;
  size_t off = 0;
  const size_t plane = (size_t)BATCH*NTOK*CH*2;       // 8.4 MB fp16 plane
  const size_t NN    = (size_t)NTOK*NTOK;             // 16.8M elements
  u16* Qh = (u16*)(ws + off); off += plane;
  u16* Kh = (u16*)(ws + off); off += plane;
  u16* Vc = (u16*)(ws + off); off += plane;
  u16* W3h = (u16*)(ws + off); off += (size_t)3*CH*CH*2;
  u16* W3l = (u16*)(ws + off); off += (size_t)3*CH*CH*2;
  // xT planes live only until proj_gemm completes; Wd overlaps them afterwards.
  const size_t xt_base = off;
  u16* xTh = (u16*)(ws + xt_base);
  u16* xTl = (u16*)(ws + xt_base + plane);
  const size_t fullW_need = xt_base + (size_t)BATCH*NN*2 + NN*4;   // ~227 MiB
  const bool fullW = ws_size >= fullW_need;
  u16* Wd = (u16*)(ws + xt_base);
  float* S = (float*)(ws + xt_base + (fullW ? (size_t)BATCH*NN*2 : NN*2));

  wsplit_kernel<<<dim3(64,3), 256, 0, stream>>>(Wq, Wk, Wv, W3h, W3l);
  xsplit_kernel<<<dim3(64,4,4), 256, 0, stream>>>(x, xTh, xTl);
  proj_gemm<<<dim3(32,2,12), 256, 0, stream>>>(xTh, xTl, W3h, W3l, Qh, Kh, Vc);

  if (fullW) {
    for (int b=0; b<BATCH; b++) {
      score_kernel<<<dim3(32,32), 256, 0, stream>>>(Qh, Kh, S, b);
      select_kernel<<<1024, 256, 0, stream>>>(S, Wd + (size_t)b*NN);
    }
    pv_gemm<<<dim3(2,64,4), 256, 0, stream>>>(Vc, Wd, out, 0, NN);
  } else {
    for (int b=0; b<BATCH; b++) {
      score_kernel<<<dim3(32,32), 256, 0, stream>>>(Qh, Kh, S, b);
      select_kernel<<<1024, 256, 0, stream>>>(S, Wd);
      pv_gemm<<<dim3(2,64,1), 256, 0, stream>>>(Vc, Wd, out, b, 0);
    }
  }
}